// Round 1
// baseline (3436.381 us; speedup 1.0000x reference)
//
#include <hip/hip_runtime.h>
#include <math.h>

#define N_NODES 100000
#define IN_CH 128
#define HID 256
#define EMB 128
#define N_PAIRS 500000
#define BN_EPS 1e-5f

#define TA 32   // nodes per block (kernel A)
#define PB 16   // pairs per block (kernel B)
#define KP 514  // pair feature dim (4*EMB + 2)
#define PPAD 20 // padded row length (floats) for [k][pair] LDS tiles; 80B keeps 16B alignment

// ---------------------------------------------------------------------------
// Kernel A: z = relu( relu(BN(clip((x-mean)/std) @ W1 + b1)) @ W2 + b2 )
// 32 nodes per block, 256 threads. Register-tiled fp32.
// ---------------------------------------------------------------------------
__global__ __launch_bounds__(256) void node_mlp_kernel(
    const float* __restrict__ x,
    const float* __restrict__ x_mean,
    const float* __restrict__ x_std,
    const float* __restrict__ W1,
    const float* __restrict__ b1,
    const float* __restrict__ bn_gamma,
    const float* __restrict__ bn_beta,
    const float* __restrict__ bn_mean,
    const float* __restrict__ bn_var,
    const float* __restrict__ W2,
    const float* __restrict__ b2,
    float* __restrict__ z)
{
    // transposed tiles: [k][node], row padded 32 -> 36 floats (16B-aligned rows)
    __shared__ __align__(16) float xfT[IN_CH][36];
    __shared__ __align__(16) float hT[HID][36];

    const int t  = threadIdx.x;
    const int n0 = blockIdx.x * TA;

    // ---- load + normalize x tile (transpose into LDS) ----
    for (int f = t; f < TA * (IN_CH / 4); f += 256) {
        const int n  = f >> 5;   // 32 float4 per node row
        const int cg = f & 31;
        float4 v = *reinterpret_cast<const float4*>(x + (size_t)(n0 + n) * IN_CH + cg * 4);
        float vv[4] = {v.x, v.y, v.z, v.w};
        #pragma unroll
        for (int e = 0; e < 4; ++e) {
            const int c = cg * 4 + e;
            float val = vv[e];
            if (!isfinite(val)) val = 0.0f;                 // nan_to_num(x, 0, 0, 0)
            val = (val - x_mean[c]) / x_std[c];
            val = fminf(fmaxf(val, -10.0f), 10.0f);
            xfT[c][n] = val;
        }
    }
    __syncthreads();

    const int i0 = t >> 6;   // node group (x8), wave-uniform -> LDS broadcast reads
    const int j  = t & 63;   // column group

    // ---- phase 1: h = relu(BN(xf @ W1 + b1)), cols j*4..+4, nodes i0*8..+8 ----
    {
        float acc[8][4];
        #pragma unroll
        for (int r = 0; r < 8; ++r)
            #pragma unroll
            for (int c = 0; c < 4; ++c) acc[r][c] = 0.0f;

        #pragma unroll 4
        for (int k = 0; k < IN_CH; ++k) {
            float a[8];
            *reinterpret_cast<float4*>(&a[0]) = *reinterpret_cast<const float4*>(&xfT[k][i0 * 8]);
            *reinterpret_cast<float4*>(&a[4]) = *reinterpret_cast<const float4*>(&xfT[k][i0 * 8 + 4]);
            float w[4];
            *reinterpret_cast<float4*>(w) = *reinterpret_cast<const float4*>(W1 + (size_t)k * HID + j * 4);
            #pragma unroll
            for (int r = 0; r < 8; ++r)
                #pragma unroll
                for (int c = 0; c < 4; ++c)
                    acc[r][c] = fmaf(a[r], w[c], acc[r][c]);
        }

        float b1v[4], gv[4], bev[4], mv[4], vv[4];
        *reinterpret_cast<float4*>(b1v) = *reinterpret_cast<const float4*>(b1 + j * 4);
        *reinterpret_cast<float4*>(gv)  = *reinterpret_cast<const float4*>(bn_gamma + j * 4);
        *reinterpret_cast<float4*>(bev) = *reinterpret_cast<const float4*>(bn_beta + j * 4);
        *reinterpret_cast<float4*>(mv)  = *reinterpret_cast<const float4*>(bn_mean + j * 4);
        *reinterpret_cast<float4*>(vv)  = *reinterpret_cast<const float4*>(bn_var + j * 4);

        #pragma unroll
        for (int c = 0; c < 4; ++c) {
            const float scale = gv[c] * rsqrtf(vv[c] + BN_EPS);
            float tmp[8];
            #pragma unroll
            for (int r = 0; r < 8; ++r) {
                const float hv = (acc[r][c] + b1v[c] - mv[c]) * scale + bev[c];
                tmp[r] = fmaxf(hv, 0.0f);
            }
            *reinterpret_cast<float4*>(&hT[j * 4 + c][i0 * 8])     = *reinterpret_cast<float4*>(&tmp[0]);
            *reinterpret_cast<float4*>(&hT[j * 4 + c][i0 * 8 + 4]) = *reinterpret_cast<float4*>(&tmp[4]);
        }
    }
    __syncthreads();

    // ---- phase 2: z = relu(h @ W2 + b2), cols j*2..+2, nodes i0*8..+8 ----
    {
        float acc[8][2];
        #pragma unroll
        for (int r = 0; r < 8; ++r) { acc[r][0] = 0.0f; acc[r][1] = 0.0f; }

        #pragma unroll 4
        for (int k = 0; k < HID; ++k) {
            float a[8];
            *reinterpret_cast<float4*>(&a[0]) = *reinterpret_cast<const float4*>(&hT[k][i0 * 8]);
            *reinterpret_cast<float4*>(&a[4]) = *reinterpret_cast<const float4*>(&hT[k][i0 * 8 + 4]);
            const float2 w = *reinterpret_cast<const float2*>(W2 + (size_t)k * EMB + j * 2);
            #pragma unroll
            for (int r = 0; r < 8; ++r) {
                acc[r][0] = fmaf(a[r], w.x, acc[r][0]);
                acc[r][1] = fmaf(a[r], w.y, acc[r][1]);
            }
        }
        const float2 b2v = *reinterpret_cast<const float2*>(b2 + j * 2);
        #pragma unroll
        for (int r = 0; r < 8; ++r) {
            float2 o;
            o.x = fmaxf(acc[r][0] + b2v.x, 0.0f);
            o.y = fmaxf(acc[r][1] + b2v.y, 0.0f);
            *reinterpret_cast<float2*>(z + (size_t)(n0 + i0 * 8 + r) * EMB + j * 2) = o;
        }
    }
}

// ---------------------------------------------------------------------------
// Kernel B: gather z[si], z[di]; pair = [src,dst,src*dst,|src-dst|,deg_s,deg_d]
// logits = relu(relu(pair@SW1+Sb1)@SW2+Sb2)@SW3+Sb3
// 16 pairs per block, 256 threads. All inner-loop LDS reads are wave-broadcast.
// ---------------------------------------------------------------------------
__global__ __launch_bounds__(256) void pair_mlp_kernel(
    const float* __restrict__ z,
    const int* __restrict__ pairs,
    const float* __restrict__ logdeg,
    const float* __restrict__ SW1, const float* __restrict__ Sb1,
    const float* __restrict__ SW2, const float* __restrict__ Sb2,
    const float* __restrict__ SW3, const float* __restrict__ Sb3,
    float* __restrict__ out)
{
    __shared__ __align__(16) float pT[KP * PPAD];    // [k][pair]  41120 B
    __shared__ __align__(16) float s1T[HID * PPAD];  // [c][pair]  20480 B
    float* const s2T = pT;                           // reuse: pT dead after s1 phase

    const int t  = threadIdx.x;
    const int p0 = blockIdx.x * PB;

    // ---- gather + build pair features (transposed into LDS) ----
    {
        const int i = t >> 4;   // pair 0..15
        const int g = t & 15;   // channel group (8 ch each)
        const int si = pairs[(size_t)(p0 + i) * 2 + 0];
        const int di = pairs[(size_t)(p0 + i) * 2 + 1];
        const float* zs = z + (size_t)si * EMB + g * 8;
        const float* zd = z + (size_t)di * EMB + g * 8;
        float sv[8], dv[8];
        *reinterpret_cast<float4*>(&sv[0]) = *reinterpret_cast<const float4*>(zs);
        *reinterpret_cast<float4*>(&sv[4]) = *reinterpret_cast<const float4*>(zs + 4);
        *reinterpret_cast<float4*>(&dv[0]) = *reinterpret_cast<const float4*>(zd);
        *reinterpret_cast<float4*>(&dv[4]) = *reinterpret_cast<const float4*>(zd + 4);
        #pragma unroll
        for (int e = 0; e < 8; ++e) {
            const int c = g * 8 + e;
            pT[c * PPAD + i]               = sv[e];
            pT[(EMB + c) * PPAD + i]       = dv[e];
            pT[(2 * EMB + c) * PPAD + i]   = sv[e] * dv[e];
            pT[(3 * EMB + c) * PPAD + i]   = fabsf(sv[e] - dv[e]);
        }
        if (g == 0) {
            pT[(4 * EMB) * PPAD + i]     = logdeg[si];
            pT[(4 * EMB + 1) * PPAD + i] = logdeg[di];
        }
    }
    __syncthreads();

    const int i0 = t >> 6;  // pair group (x4), wave-uniform -> broadcast reads
    const int j  = t & 63;  // col group

    // ---- s1 = relu(pair @ SW1 + Sb1): [16 x 514] @ [514 x 256] ----
    {
        float acc[4][4];
        #pragma unroll
        for (int r = 0; r < 4; ++r)
            #pragma unroll
            for (int c = 0; c < 4; ++c) acc[r][c] = 0.0f;

        #pragma unroll 2
        for (int k = 0; k < KP; ++k) {
            float a[4], w[4];
            *reinterpret_cast<float4*>(a) = *reinterpret_cast<const float4*>(&pT[k * PPAD + i0 * 4]);
            *reinterpret_cast<float4*>(w) = *reinterpret_cast<const float4*>(SW1 + (size_t)k * HID + j * 4);
            #pragma unroll
            for (int r = 0; r < 4; ++r)
                #pragma unroll
                for (int c = 0; c < 4; ++c)
                    acc[r][c] = fmaf(a[r], w[c], acc[r][c]);
        }
        float bb[4];
        *reinterpret_cast<float4*>(bb) = *reinterpret_cast<const float4*>(Sb1 + j * 4);
        #pragma unroll
        for (int c = 0; c < 4; ++c) {
            float4 v;
            v.x = fmaxf(acc[0][c] + bb[c], 0.0f);
            v.y = fmaxf(acc[1][c] + bb[c], 0.0f);
            v.z = fmaxf(acc[2][c] + bb[c], 0.0f);
            v.w = fmaxf(acc[3][c] + bb[c], 0.0f);
            *reinterpret_cast<float4*>(&s1T[(j * 4 + c) * PPAD + i0 * 4]) = v;
        }
    }
    __syncthreads();

    // ---- s2 = relu(s1 @ SW2 + Sb2): [16 x 256] @ [256 x 128] ----
    {
        float acc[4][2];
        #pragma unroll
        for (int r = 0; r < 4; ++r) { acc[r][0] = 0.0f; acc[r][1] = 0.0f; }

        #pragma unroll 4
        for (int k = 0; k < HID; ++k) {
            float a[4];
            *reinterpret_cast<float4*>(a) = *reinterpret_cast<const float4*>(&s1T[k * PPAD + i0 * 4]);
            const float2 w = *reinterpret_cast<const float2*>(SW2 + (size_t)k * (HID / 2) + j * 2);
            #pragma unroll
            for (int r = 0; r < 4; ++r) {
                acc[r][0] = fmaf(a[r], w.x, acc[r][0]);
                acc[r][1] = fmaf(a[r], w.y, acc[r][1]);
            }
        }
        const float2 bb = *reinterpret_cast<const float2*>(Sb2 + j * 2);
        #pragma unroll
        for (int c = 0; c < 2; ++c) {
            float4 v;
            v.x = fmaxf(acc[0][c] + ((c == 0) ? bb.x : bb.y), 0.0f);
            v.y = fmaxf(acc[1][c] + ((c == 0) ? bb.x : bb.y), 0.0f);
            v.z = fmaxf(acc[2][c] + ((c == 0) ? bb.x : bb.y), 0.0f);
            v.w = fmaxf(acc[3][c] + ((c == 0) ? bb.x : bb.y), 0.0f);
            *reinterpret_cast<float4*>(&s2T[(j * 2 + c) * PPAD + i0 * 4]) = v;
        }
    }
    __syncthreads();

    // ---- logits = s2 @ SW3 + Sb3, then nan_to_num(nan=0, +inf=20, -inf=-20) ----
    if (t < PB * 8) {
        const int i  = t >> 3;
        const int kk = t & 7;
        float sum = 0.0f;
        #pragma unroll
        for (int m = 0; m < 16; ++m) {
            const int k = kk + m * 8;
            sum = fmaf(s2T[k * PPAD + i], SW3[k], sum);
        }
        sum += __shfl_xor(sum, 1);
        sum += __shfl_xor(sum, 2);
        sum += __shfl_xor(sum, 4);
        if (kk == 0) {
            float v = sum + Sb3[0];
            if (isnan(v)) v = 0.0f;
            else if (isinf(v)) v = (v > 0.0f) ? 20.0f : -20.0f;
            out[p0 + i] = v;
        }
    }
}

// ---------------------------------------------------------------------------
extern "C" void kernel_launch(void* const* d_in, const int* in_sizes, int n_in,
                              void* d_out, int out_size, void* d_ws, size_t ws_size,
                              hipStream_t stream)
{
    const float* x        = (const float*)d_in[0];
    // d_in[1] = edge_index : unused by the reference
    const int*   pairs    = (const int*)d_in[2];
    const float* x_mean   = (const float*)d_in[3];
    const float* x_std    = (const float*)d_in[4];
    const float* logdeg   = (const float*)d_in[5];
    const float* W1       = (const float*)d_in[6];
    const float* b1       = (const float*)d_in[7];
    const float* bn_gamma = (const float*)d_in[8];
    const float* bn_beta  = (const float*)d_in[9];
    const float* bn_mean  = (const float*)d_in[10];
    const float* bn_var   = (const float*)d_in[11];
    const float* W2       = (const float*)d_in[12];
    const float* b2       = (const float*)d_in[13];
    const float* SW1      = (const float*)d_in[14];
    const float* Sb1      = (const float*)d_in[15];
    const float* SW2      = (const float*)d_in[16];
    const float* Sb2      = (const float*)d_in[17];
    const float* SW3      = (const float*)d_in[18];
    const float* Sb3      = (const float*)d_in[19];

    float* outp = (float*)d_out;
    float* zbuf = (float*)d_ws;   // 100000 x 128 fp32 = 51.2 MB

    node_mlp_kernel<<<N_NODES / TA, 256, 0, stream>>>(
        x, x_mean, x_std, W1, b1, bn_gamma, bn_beta, bn_mean, bn_var, W2, b2, zbuf);

    pair_mlp_kernel<<<N_PAIRS / PB, 256, 0, stream>>>(
        zbuf, pairs, logdeg, SW1, Sb1, SW2, Sb2, SW3, Sb3, outp);
}

// Round 2
// 842.300 us; speedup vs baseline: 4.0798x; 4.0798x over previous
//
#include <hip/hip_runtime.h>
#include <math.h>

typedef unsigned short u16;
typedef __attribute__((ext_vector_type(8))) short bf16x8;
typedef __attribute__((ext_vector_type(8))) unsigned short u16x8;
typedef __attribute__((ext_vector_type(4))) float f32x4;

#define N_NODES 100000
#define IN_CH 128
#define HID 256
#define EMB 128
#define N_PAIRS 500000
#define BN_EPS 1e-5f

#define TA 32   // nodes per block (kernel A)
#define PBM 32  // pairs per block (kernel B)

// ---- bf16 split helpers (round-to-nearest-even) ----
__device__ __forceinline__ u16 f2bf(float f) {
    unsigned u = __builtin_bit_cast(unsigned, f);
    unsigned r = u + 0x7FFFu + ((u >> 16) & 1u);
    return (u16)(r >> 16);
}
__device__ __forceinline__ float bf2f(u16 h) {
    unsigned u = ((unsigned)h) << 16;
    return __builtin_bit_cast(float, u);
}

// ---------------------------------------------------------------------------
// Weight prep: SW1[512][256] -> W1F hi/lo, SW2[256][128] -> W2F hi/lo, both in
// MFMA B-fragment-linear layout: idx = ((cg*KS + ks)*64 + lane)*8 + j
// where col = cg*16 + (lane&15), k = ks*32 + (lane>>4)*8 + j.
// ---------------------------------------------------------------------------
__global__ __launch_bounds__(256) void prep_weights(
    const float* __restrict__ SW1, const float* __restrict__ SW2,
    u16* __restrict__ w1h, u16* __restrict__ w1l,
    u16* __restrict__ w2h, u16* __restrict__ w2l)
{
    const int tid = blockIdx.x * 256 + threadIdx.x;
    if (tid < 131072) {
        const int cg = tid >> 13, ks = (tid >> 9) & 15, l = (tid >> 3) & 63, j = tid & 7;
        const int col = (cg << 4) + (l & 15);
        const int k   = (ks << 5) + ((l >> 4) << 3) + j;
        const float v = SW1[(size_t)k * HID + col];
        const u16 h = f2bf(v);
        w1h[tid] = h;
        w1l[tid] = f2bf(v - bf2f(h));
    } else if (tid < 131072 + 32768) {
        const int t2 = tid - 131072;
        const int cg = t2 >> 12, ks = (t2 >> 9) & 7, l = (t2 >> 3) & 63, j = t2 & 7;
        const int col = (cg << 4) + (l & 15);
        const int k   = (ks << 5) + ((l >> 4) << 3) + j;
        const float v = SW2[(size_t)k * (HID / 2) + col];
        const u16 h = f2bf(v);
        w2h[t2] = h;
        w2l[t2] = f2bf(v - bf2f(h));
    }
}

// ---------------------------------------------------------------------------
// Kernel A: z = relu( relu(BN(clip((x-mean)/std) @ W1 + b1)) @ W2 + b2 )
// (unchanged from round 1 — fp32 register-tiled)
// ---------------------------------------------------------------------------
__global__ __launch_bounds__(256) void node_mlp_kernel(
    const float* __restrict__ x,
    const float* __restrict__ x_mean,
    const float* __restrict__ x_std,
    const float* __restrict__ W1,
    const float* __restrict__ b1,
    const float* __restrict__ bn_gamma,
    const float* __restrict__ bn_beta,
    const float* __restrict__ bn_mean,
    const float* __restrict__ bn_var,
    const float* __restrict__ W2,
    const float* __restrict__ b2,
    float* __restrict__ z)
{
    __shared__ __align__(16) float xfT[IN_CH][36];
    __shared__ __align__(16) float hT[HID][36];

    const int t  = threadIdx.x;
    const int n0 = blockIdx.x * TA;

    for (int f = t; f < TA * (IN_CH / 4); f += 256) {
        const int n  = f >> 5;
        const int cg = f & 31;
        float4 v = *reinterpret_cast<const float4*>(x + (size_t)(n0 + n) * IN_CH + cg * 4);
        float vv[4] = {v.x, v.y, v.z, v.w};
        #pragma unroll
        for (int e = 0; e < 4; ++e) {
            const int c = cg * 4 + e;
            float val = vv[e];
            if (!isfinite(val)) val = 0.0f;
            val = (val - x_mean[c]) / x_std[c];
            val = fminf(fmaxf(val, -10.0f), 10.0f);
            xfT[c][n] = val;
        }
    }
    __syncthreads();

    const int i0 = t >> 6;
    const int j  = t & 63;

    {
        float acc[8][4];
        #pragma unroll
        for (int r = 0; r < 8; ++r)
            #pragma unroll
            for (int c = 0; c < 4; ++c) acc[r][c] = 0.0f;

        #pragma unroll 4
        for (int k = 0; k < IN_CH; ++k) {
            float a[8];
            *reinterpret_cast<float4*>(&a[0]) = *reinterpret_cast<const float4*>(&xfT[k][i0 * 8]);
            *reinterpret_cast<float4*>(&a[4]) = *reinterpret_cast<const float4*>(&xfT[k][i0 * 8 + 4]);
            float w[4];
            *reinterpret_cast<float4*>(w) = *reinterpret_cast<const float4*>(W1 + (size_t)k * HID + j * 4);
            #pragma unroll
            for (int r = 0; r < 8; ++r)
                #pragma unroll
                for (int c = 0; c < 4; ++c)
                    acc[r][c] = fmaf(a[r], w[c], acc[r][c]);
        }

        float b1v[4], gv[4], bev[4], mv[4], vv[4];
        *reinterpret_cast<float4*>(b1v) = *reinterpret_cast<const float4*>(b1 + j * 4);
        *reinterpret_cast<float4*>(gv)  = *reinterpret_cast<const float4*>(bn_gamma + j * 4);
        *reinterpret_cast<float4*>(bev) = *reinterpret_cast<const float4*>(bn_beta + j * 4);
        *reinterpret_cast<float4*>(mv)  = *reinterpret_cast<const float4*>(bn_mean + j * 4);
        *reinterpret_cast<float4*>(vv)  = *reinterpret_cast<const float4*>(bn_var + j * 4);

        #pragma unroll
        for (int c = 0; c < 4; ++c) {
            const float scale = gv[c] * rsqrtf(vv[c] + BN_EPS);
            float tmp[8];
            #pragma unroll
            for (int r = 0; r < 8; ++r) {
                const float hv = (acc[r][c] + b1v[c] - mv[c]) * scale + bev[c];
                tmp[r] = fmaxf(hv, 0.0f);
            }
            *reinterpret_cast<float4*>(&hT[j * 4 + c][i0 * 8])     = *reinterpret_cast<float4*>(&tmp[0]);
            *reinterpret_cast<float4*>(&hT[j * 4 + c][i0 * 8 + 4]) = *reinterpret_cast<float4*>(&tmp[4]);
        }
    }
    __syncthreads();

    {
        float acc[8][2];
        #pragma unroll
        for (int r = 0; r < 8; ++r) { acc[r][0] = 0.0f; acc[r][1] = 0.0f; }

        #pragma unroll 4
        for (int k = 0; k < HID; ++k) {
            float a[8];
            *reinterpret_cast<float4*>(&a[0]) = *reinterpret_cast<const float4*>(&hT[k][i0 * 8]);
            *reinterpret_cast<float4*>(&a[4]) = *reinterpret_cast<const float4*>(&hT[k][i0 * 8 + 4]);
            const float2 w = *reinterpret_cast<const float2*>(W2 + (size_t)k * EMB + j * 2);
            #pragma unroll
            for (int r = 0; r < 8; ++r) {
                acc[r][0] = fmaf(a[r], w.x, acc[r][0]);
                acc[r][1] = fmaf(a[r], w.y, acc[r][1]);
            }
        }
        const float2 b2v = *reinterpret_cast<const float2*>(b2 + j * 2);
        #pragma unroll
        for (int r = 0; r < 8; ++r) {
            float2 o;
            o.x = fmaxf(acc[r][0] + b2v.x, 0.0f);
            o.y = fmaxf(acc[r][1] + b2v.y, 0.0f);
            *reinterpret_cast<float2*>(z + (size_t)(n0 + i0 * 8 + r) * EMB + j * 2) = o;
        }
    }
}

// ---------------------------------------------------------------------------
// Kernel B (MFMA): per block 32 pairs, 4 waves.
//   layer1: [32 x 512] @ [512 x 256]  (split-3 bf16 MFMA, logdeg rank-2 in epilogue)
//   layer2: [32 x 256] @ [256 x 128]  (split-3 bf16 MFMA)
//   layer3: [32 x 128] @ [128 x 1]    (fp32 VALU + shuffle reduce)
// A / s1 in LDS fragment-linear layout (conflict-free ds_read_b128).
// ---------------------------------------------------------------------------
__global__ __launch_bounds__(256, 2) void pair_mfma_kernel(
    const float* __restrict__ z,
    const int* __restrict__ pairs,
    const float* __restrict__ logdeg,
    const u16* __restrict__ w1h, const u16* __restrict__ w1l,
    const u16* __restrict__ w2h, const u16* __restrict__ w2l,
    const float* __restrict__ SW1, const float* __restrict__ Sb1,
    const float* __restrict__ Sb2,
    const float* __restrict__ SW3, const float* __restrict__ Sb3,
    float* __restrict__ out)
{
    __shared__ __align__(16) u16 Ahi[PBM * 512];   // 32 KB, frag-linear
    __shared__ __align__(16) u16 Alo[PBM * 512];   // 32 KB, frag-linear

    const int t    = threadIdx.x;
    const int p0   = blockIdx.x * PBM;
    const int lane = t & 63;
    const int wid  = t >> 6;
    const int l15  = lane & 15;
    const int l4   = lane >> 4;

    // ---- phase 0: gather z rows, build 512-dim features, split hi/lo into LDS ----
    {
        const int i = t >> 3;    // pair row 0..31
        const int g = t & 7;     // 16-channel group
        const int si = pairs[(size_t)(p0 + i) * 2 + 0];
        const int di = pairs[(size_t)(p0 + i) * 2 + 1];
        const float* zs = z + (size_t)si * EMB + g * 16;
        const float* zd = z + (size_t)di * EMB + g * 16;
        float s[16], d[16];
        #pragma unroll
        for (int q = 0; q < 4; ++q) {
            *reinterpret_cast<float4*>(&s[q * 4]) = *reinterpret_cast<const float4*>(zs + q * 4);
            *reinterpret_cast<float4*>(&d[q * 4]) = *reinterpret_cast<const float4*>(zd + q * 4);
        }
        float p[16], ad[16];
        #pragma unroll
        for (int e = 0; e < 16; ++e) { p[e] = s[e] * d[e]; ad[e] = fabsf(s[e] - d[e]); }

        const int mgrp = i >> 4;
        const int r15  = i & 15;
        // store one 16-channel run at k0 (multiple of 16)
        #define STORE16(vals, k0) { \
            const int ks   = (k0) >> 5; \
            const int sub0 = ((k0) >> 3) & 3; \
            u16x8 h0, h1, l0, l1; \
            _Pragma("unroll") \
            for (int jj = 0; jj < 8; ++jj) { \
                u16 hh = f2bf((vals)[jj]);      h0[jj] = hh; l0[jj] = f2bf((vals)[jj] - bf2f(hh)); \
                u16 hh2 = f2bf((vals)[8 + jj]); h1[jj] = hh2; l1[jj] = f2bf((vals)[8 + jj] - bf2f(hh2)); \
            } \
            const int idx0 = (((mgrp * 16 + ks) * 64) + (r15 + 16 * sub0)) * 8; \
            const int idx1 = (((mgrp * 16 + ks) * 64) + (r15 + 16 * (sub0 + 1))) * 8; \
            *reinterpret_cast<u16x8*>(&Ahi[idx0]) = h0; \
            *reinterpret_cast<u16x8*>(&Ahi[idx1]) = h1; \
            *reinterpret_cast<u16x8*>(&Alo[idx0]) = l0; \
            *reinterpret_cast<u16x8*>(&Alo[idx1]) = l1; }

        STORE16(s,  g * 16);
        STORE16(d,  128 + g * 16);
        STORE16(p,  256 + g * 16);
        STORE16(ad, 384 + g * 16);
        #undef STORE16
    }

    // ---- per-thread epilogue constants (global reads, L1/L2-hot) ----
    float ldS[8], ldD[8];
    #pragma unroll
    for (int m = 0; m < 2; ++m)
        #pragma unroll
        for (int r = 0; r < 4; ++r) {
            const int row = 16 * m + l4 * 4 + r;
            const int ssi = pairs[(size_t)(p0 + row) * 2 + 0];
            const int ddi = pairs[(size_t)(p0 + row) * 2 + 1];
            ldS[m * 4 + r] = logdeg[ssi];
            ldD[m * 4 + r] = logdeg[ddi];
        }
    const int n0 = wid * 64;
    float w5a[4], w5b[4], sb1v[4];
    #pragma unroll
    for (int nf = 0; nf < 4; ++nf) {
        const int n = n0 + nf * 16 + l15;
        w5a[nf]  = SW1[(size_t)512 * HID + n];
        w5b[nf]  = SW1[(size_t)513 * HID + n];
        sb1v[nf] = Sb1[n];
    }

    __syncthreads();

    // ---- layer 1: MFMA over K=512 (16 K-steps), N-slice = 64 cols per wave ----
    f32x4 acc[2][4];
    #pragma unroll
    for (int m = 0; m < 2; ++m)
        #pragma unroll
        for (int nf = 0; nf < 4; ++nf) acc[m][nf] = (f32x4){0.f, 0.f, 0.f, 0.f};

    {
        const char* Ah = (const char*)Ahi;
        const char* Al = (const char*)Alo;
        const char* Bh = (const char*)w1h;
        const char* Bl = (const char*)w1l;
        const int aoff = lane * 16;

        #pragma unroll 2
        for (int ks = 0; ks < 16; ++ks) {
            bf16x8 ah0 = *reinterpret_cast<const bf16x8*>(Ah + ks * 1024 + aoff);
            bf16x8 ah1 = *reinterpret_cast<const bf16x8*>(Ah + 16384 + ks * 1024 + aoff);
            bf16x8 al0 = *reinterpret_cast<const bf16x8*>(Al + ks * 1024 + aoff);
            bf16x8 al1 = *reinterpret_cast<const bf16x8*>(Al + 16384 + ks * 1024 + aoff);
            #pragma unroll
            for (int nf = 0; nf < 4; ++nf) {
                const int cg = wid * 4 + nf;
                const size_t bo = (size_t)cg * 16384 + ks * 1024 + aoff;
                bf16x8 bh = *reinterpret_cast<const bf16x8*>(Bh + bo);
                bf16x8 bl = *reinterpret_cast<const bf16x8*>(Bl + bo);
                acc[0][nf] = __builtin_amdgcn_mfma_f32_16x16x32_bf16(ah0, bh, acc[0][nf], 0, 0, 0);
                acc[1][nf] = __builtin_amdgcn_mfma_f32_16x16x32_bf16(ah1, bh, acc[1][nf], 0, 0, 0);
                acc[0][nf] = __builtin_amdgcn_mfma_f32_16x16x32_bf16(al0, bh, acc[0][nf], 0, 0, 0);
                acc[1][nf] = __builtin_amdgcn_mfma_f32_16x16x32_bf16(al1, bh, acc[1][nf], 0, 0, 0);
                acc[0][nf] = __builtin_amdgcn_mfma_f32_16x16x32_bf16(ah0, bl, acc[0][nf], 0, 0, 0);
                acc[1][nf] = __builtin_amdgcn_mfma_f32_16x16x32_bf16(ah1, bl, acc[1][nf], 0, 0, 0);
            }
        }
    }

    __syncthreads();   // all waves done reading A

    // ---- epilogue 1: + bias + logdeg rank-2, relu, split -> s1 (frag-linear in Ahi) ----
    u16* s1h = Ahi;               // [32][256] frag-linear, 8192 u16
    u16* s1l = Ahi + 8192;
    #pragma unroll
    for (int m = 0; m < 2; ++m)
        #pragma unroll
        for (int nf = 0; nf < 4; ++nf) {
            const int n = n0 + nf * 16 + l15;
            #pragma unroll
            for (int r = 0; r < 4; ++r) {
                const int row = 16 * m + l4 * 4 + r;
                float v = acc[m][nf][r] + sb1v[nf];
                v = fmaf(ldS[m * 4 + r], w5a[nf], v);
                v = fmaf(ldD[m * 4 + r], w5b[nf], v);
                v = fmaxf(v, 0.0f);
                const u16 h = f2bf(v);
                const float lo = v - bf2f(h);
                const int idx = (((m * 8 + (n >> 5)) * 64) + ((row & 15) + 16 * ((n >> 3) & 3))) * 8 + (n & 7);
                s1h[idx] = h;
                s1l[idx] = f2bf(lo);
            }
        }

    __syncthreads();

    // ---- layer 2: MFMA over K=256 (8 K-steps), N-slice = 32 cols per wave ----
    f32x4 acc2[2][2];
    #pragma unroll
    for (int m = 0; m < 2; ++m)
        #pragma unroll
        for (int nf = 0; nf < 2; ++nf) acc2[m][nf] = (f32x4){0.f, 0.f, 0.f, 0.f};

    {
        const char* Ah = (const char*)s1h;
        const char* Al = (const char*)s1l;
        const char* Bh = (const char*)w2h;
        const char* Bl = (const char*)w2l;
        const int aoff = lane * 16;

        #pragma unroll 2
        for (int ks = 0; ks < 8; ++ks) {
            bf16x8 ah0 = *reinterpret_cast<const bf16x8*>(Ah + ks * 1024 + aoff);
            bf16x8 ah1 = *reinterpret_cast<const bf16x8*>(Ah + 8192 + ks * 1024 + aoff);
            bf16x8 al0 = *reinterpret_cast<const bf16x8*>(Al + ks * 1024 + aoff);
            bf16x8 al1 = *reinterpret_cast<const bf16x8*>(Al + 8192 + ks * 1024 + aoff);
            #pragma unroll
            for (int nf = 0; nf < 2; ++nf) {
                const int cg = wid * 2 + nf;
                const size_t bo = (size_t)cg * 8192 + ks * 1024 + aoff;
                bf16x8 bh = *reinterpret_cast<const bf16x8*>(Bh + bo);
                bf16x8 bl = *reinterpret_cast<const bf16x8*>(Bl + bo);
                acc2[0][nf] = __builtin_amdgcn_mfma_f32_16x16x32_bf16(ah0, bh, acc2[0][nf], 0, 0, 0);
                acc2[1][nf] = __builtin_amdgcn_mfma_f32_16x16x32_bf16(ah1, bh, acc2[1][nf], 0, 0, 0);
                acc2[0][nf] = __builtin_amdgcn_mfma_f32_16x16x32_bf16(al0, bh, acc2[0][nf], 0, 0, 0);
                acc2[1][nf] = __builtin_amdgcn_mfma_f32_16x16x32_bf16(al1, bh, acc2[1][nf], 0, 0, 0);
                acc2[0][nf] = __builtin_amdgcn_mfma_f32_16x16x32_bf16(ah0, bl, acc2[0][nf], 0, 0, 0);
                acc2[1][nf] = __builtin_amdgcn_mfma_f32_16x16x32_bf16(ah1, bl, acc2[1][nf], 0, 0, 0);
            }
        }
    }

    // ---- epilogue 2: + bias, relu -> s2 fp32 [32][132] in Alo region ----
    float* s2f = (float*)Alo;
    const int n0b = wid * 32;
    #pragma unroll
    for (int m = 0; m < 2; ++m)
        #pragma unroll
        for (int nf = 0; nf < 2; ++nf) {
            const int n2 = n0b + nf * 16 + l15;
            const float bias = Sb2[n2];
            #pragma unroll
            for (int r = 0; r < 4; ++r) {
                const int row = 16 * m + l4 * 4 + r;
                s2f[row * 132 + n2] = fmaxf(acc2[m][nf][r] + bias, 0.0f);
            }
        }

    __syncthreads();

    // ---- layer 3: logits = s2 @ SW3 + Sb3, nan_to_num ----
    {
        const int i  = t >> 3;
        const int kk = t & 7;
        float sum = 0.0f;
        #pragma unroll
        for (int mm = 0; mm < 16; ++mm) {
            const int k = kk + 8 * mm;
            sum = fmaf(s2f[i * 132 + k], SW3[k], sum);
        }
        sum += __shfl_xor(sum, 1);
        sum += __shfl_xor(sum, 2);
        sum += __shfl_xor(sum, 4);
        if (kk == 0) {
            float v = sum + Sb3[0];
            if (isnan(v)) v = 0.0f;
            else if (isinf(v)) v = (v > 0.0f) ? 20.0f : -20.0f;
            out[p0 + i] = v;
        }
    }
}

// ---------------------------------------------------------------------------
extern "C" void kernel_launch(void* const* d_in, const int* in_sizes, int n_in,
                              void* d_out, int out_size, void* d_ws, size_t ws_size,
                              hipStream_t stream)
{
    const float* x        = (const float*)d_in[0];
    // d_in[1] = edge_index : unused by the reference
    const int*   pairs    = (const int*)d_in[2];
    const float* x_mean   = (const float*)d_in[3];
    const float* x_std    = (const float*)d_in[4];
    const float* logdeg   = (const float*)d_in[5];
    const float* W1       = (const float*)d_in[6];
    const float* b1       = (const float*)d_in[7];
    const float* bn_gamma = (const float*)d_in[8];
    const float* bn_beta  = (const float*)d_in[9];
    const float* bn_mean  = (const float*)d_in[10];
    const float* bn_var   = (const float*)d_in[11];
    const float* W2       = (const float*)d_in[12];
    const float* b2       = (const float*)d_in[13];
    const float* SW1      = (const float*)d_in[14];
    const float* Sb1      = (const float*)d_in[15];
    const float* SW2      = (const float*)d_in[16];
    const float* Sb2      = (const float*)d_in[17];
    const float* SW3      = (const float*)d_in[18];
    const float* Sb3      = (const float*)d_in[19];

    float* outp = (float*)d_out;

    // ws layout
    char* wsb = (char*)d_ws;
    float* zbuf = (float*)wsb;                          // 100000*128*4 = 51,200,000 B
    u16* w1h = (u16*)(wsb + 51200000);                  // 262144 B
    u16* w1l = (u16*)(wsb + 51462144);                  // 262144 B
    u16* w2h = (u16*)(wsb + 51724288);                  // 65536 B
    u16* w2l = (u16*)(wsb + 51789824);                  // 65536 B

    prep_weights<<<640, 256, 0, stream>>>(SW1, SW2, w1h, w1l, w2h, w2l);

    node_mlp_kernel<<<N_NODES / TA, 256, 0, stream>>>(
        x, x_mean, x_std, W1, b1, bn_gamma, bn_beta, bn_mean, bn_var, W2, b2, zbuf);

    pair_mfma_kernel<<<N_PAIRS / PBM, 256, 0, stream>>>(
        zbuf, pairs, logdeg, w1h, w1l, w2h, w2l, SW1, Sb1, Sb2, SW3, Sb3, outp);
}

// Round 3
// 806.006 us; speedup vs baseline: 4.2635x; 1.0450x over previous
//
#include <hip/hip_runtime.h>
#include <math.h>

typedef unsigned short u16;
typedef __attribute__((ext_vector_type(8))) short bf16x8;
typedef __attribute__((ext_vector_type(4))) unsigned short u16x4;
typedef __attribute__((ext_vector_type(8))) unsigned short u16x8;
typedef __attribute__((ext_vector_type(4))) float f32x4;

#define N_NODES 100000
#define IN_CH 128
#define HID 256
#define EMB 128
#define N_PAIRS 500000
#define BN_EPS 1e-5f

#define TA 32   // nodes per block (kernel A)
#define PBM 32  // pairs per block (kernel B)

// ---- bf16 split helpers (round-to-nearest-even) ----
__device__ __forceinline__ u16 f2bf(float f) {
    unsigned u = __builtin_bit_cast(unsigned, f);
    unsigned r = u + 0x7FFFu + ((u >> 16) & 1u);
    return (u16)(r >> 16);
}
__device__ __forceinline__ float bf2f(u16 h) {
    unsigned u = ((unsigned)h) << 16;
    return __builtin_bit_cast(float, u);
}

// ---------------------------------------------------------------------------
// Weight prep into MFMA *A-operand* fragment-linear layout (weights are the
// first/M-side operand now):  idx = ((mt*KS + ks)*64 + l)*8 + j
// value = W[k][n] with n = mt*16 + (l&15), k = ks*32 + (l>>4)*8 + j.
// ---------------------------------------------------------------------------
__global__ __launch_bounds__(256) void prep_weights(
    const float* __restrict__ SW1, const float* __restrict__ SW2,
    u16* __restrict__ w1h, u16* __restrict__ w1l,
    u16* __restrict__ w2h, u16* __restrict__ w2l)
{
    const int tid = blockIdx.x * 256 + threadIdx.x;
    if (tid < 131072) {                       // W1^T frags: 16 mt x 16 ks
        const int j = tid & 7, l = (tid >> 3) & 63, ks = (tid >> 9) & 15, mt = tid >> 13;
        const int n = mt * 16 + (l & 15);
        const int k = ks * 32 + ((l >> 4) << 3) + j;
        const float v = SW1[(size_t)k * HID + n];
        const u16 h = f2bf(v);
        w1h[tid] = h;
        w1l[tid] = f2bf(v - bf2f(h));
    } else if (tid < 131072 + 32768) {        // W2^T frags: 8 mt x 8 ks
        const int t2 = tid - 131072;
        const int j = t2 & 7, l = (t2 >> 3) & 63, ks = (t2 >> 9) & 7, mt = t2 >> 12;
        const int n = mt * 16 + (l & 15);
        const int k = ks * 32 + ((l >> 4) << 3) + j;
        const float v = SW2[(size_t)k * (HID / 2) + n];
        const u16 h = f2bf(v);
        w2h[t2] = h;
        w2l[t2] = f2bf(v - bf2f(h));
    }
}

// ---------------------------------------------------------------------------
// Kernel A: z = relu( relu(BN(clip((x-mean)/std) @ W1 + b1)) @ W2 + b2 )
// (unchanged — fp32 register-tiled)
// ---------------------------------------------------------------------------
__global__ __launch_bounds__(256) void node_mlp_kernel(
    const float* __restrict__ x,
    const float* __restrict__ x_mean,
    const float* __restrict__ x_std,
    const float* __restrict__ W1,
    const float* __restrict__ b1,
    const float* __restrict__ bn_gamma,
    const float* __restrict__ bn_beta,
    const float* __restrict__ bn_mean,
    const float* __restrict__ bn_var,
    const float* __restrict__ W2,
    const float* __restrict__ b2,
    float* __restrict__ z)
{
    __shared__ __align__(16) float xfT[IN_CH][36];
    __shared__ __align__(16) float hT[HID][36];

    const int t  = threadIdx.x;
    const int n0 = blockIdx.x * TA;

    for (int f = t; f < TA * (IN_CH / 4); f += 256) {
        const int n  = f >> 5;
        const int cg = f & 31;
        float4 v = *reinterpret_cast<const float4*>(x + (size_t)(n0 + n) * IN_CH + cg * 4);
        float vv[4] = {v.x, v.y, v.z, v.w};
        #pragma unroll
        for (int e = 0; e < 4; ++e) {
            const int c = cg * 4 + e;
            float val = vv[e];
            if (!isfinite(val)) val = 0.0f;
            val = (val - x_mean[c]) / x_std[c];
            val = fminf(fmaxf(val, -10.0f), 10.0f);
            xfT[c][n] = val;
        }
    }
    __syncthreads();

    const int i0 = t >> 6;
    const int j  = t & 63;

    {
        float acc[8][4];
        #pragma unroll
        for (int r = 0; r < 8; ++r)
            #pragma unroll
            for (int c = 0; c < 4; ++c) acc[r][c] = 0.0f;

        #pragma unroll 4
        for (int k = 0; k < IN_CH; ++k) {
            float a[8];
            *reinterpret_cast<float4*>(&a[0]) = *reinterpret_cast<const float4*>(&xfT[k][i0 * 8]);
            *reinterpret_cast<float4*>(&a[4]) = *reinterpret_cast<const float4*>(&xfT[k][i0 * 8 + 4]);
            float w[4];
            *reinterpret_cast<float4*>(w) = *reinterpret_cast<const float4*>(W1 + (size_t)k * HID + j * 4);
            #pragma unroll
            for (int r = 0; r < 8; ++r)
                #pragma unroll
                for (int c = 0; c < 4; ++c)
                    acc[r][c] = fmaf(a[r], w[c], acc[r][c]);
        }

        float b1v[4], gv[4], bev[4], mv[4], vv[4];
        *reinterpret_cast<float4*>(b1v) = *reinterpret_cast<const float4*>(b1 + j * 4);
        *reinterpret_cast<float4*>(gv)  = *reinterpret_cast<const float4*>(bn_gamma + j * 4);
        *reinterpret_cast<float4*>(bev) = *reinterpret_cast<const float4*>(bn_beta + j * 4);
        *reinterpret_cast<float4*>(mv)  = *reinterpret_cast<const float4*>(bn_mean + j * 4);
        *reinterpret_cast<float4*>(vv)  = *reinterpret_cast<const float4*>(bn_var + j * 4);

        #pragma unroll
        for (int c = 0; c < 4; ++c) {
            const float scale = gv[c] * rsqrtf(vv[c] + BN_EPS);
            float tmp[8];
            #pragma unroll
            for (int r = 0; r < 8; ++r) {
                const float hv = (acc[r][c] + b1v[c] - mv[c]) * scale + bev[c];
                tmp[r] = fmaxf(hv, 0.0f);
            }
            *reinterpret_cast<float4*>(&hT[j * 4 + c][i0 * 8])     = *reinterpret_cast<float4*>(&tmp[0]);
            *reinterpret_cast<float4*>(&hT[j * 4 + c][i0 * 8 + 4]) = *reinterpret_cast<float4*>(&tmp[4]);
        }
    }
    __syncthreads();

    {
        float acc[8][2];
        #pragma unroll
        for (int r = 0; r < 8; ++r) { acc[r][0] = 0.0f; acc[r][1] = 0.0f; }

        #pragma unroll 4
        for (int k = 0; k < HID; ++k) {
            float a[8];
            *reinterpret_cast<float4*>(&a[0]) = *reinterpret_cast<const float4*>(&hT[k][i0 * 8]);
            *reinterpret_cast<float4*>(&a[4]) = *reinterpret_cast<const float4*>(&hT[k][i0 * 8 + 4]);
            const float2 w = *reinterpret_cast<const float2*>(W2 + (size_t)k * EMB + j * 2);
            #pragma unroll
            for (int r = 0; r < 8; ++r) {
                acc[r][0] = fmaf(a[r], w.x, acc[r][0]);
                acc[r][1] = fmaf(a[r], w.y, acc[r][1]);
            }
        }
        const float2 b2v = *reinterpret_cast<const float2*>(b2 + j * 2);
        #pragma unroll
        for (int r = 0; r < 8; ++r) {
            float2 o;
            o.x = fmaxf(acc[r][0] + b2v.x, 0.0f);
            o.y = fmaxf(acc[r][1] + b2v.y, 0.0f);
            *reinterpret_cast<float2*>(z + (size_t)(n0 + i0 * 8 + r) * EMB + j * 2) = o;
        }
    }
}

// ---------------------------------------------------------------------------
// Kernel B (MFMA, swapped operands): per block 32 pairs, 4 waves (256 thr).
// C^T = W^T @ feat^T so acc holds n-runs per lane -> packed b64 s1 stores and
// register-local final reduction. All LDS ops conflict-free by construction.
// Feature frag layout (B-operand): elem = half*16384 + (mgrp*16+ks)*512 + l*8 + j
//   <-> feat[pair = mgrp*16 + (l&15)][k = ks*32 + (l>>4)*8 + j]
// ---------------------------------------------------------------------------
__global__ __launch_bounds__(256, 2) void pair_mfma_kernel(
    const float* __restrict__ z,
    const int* __restrict__ pairs,
    const float* __restrict__ logdeg,
    const u16* __restrict__ w1h, const u16* __restrict__ w1l,
    const u16* __restrict__ w2h, const u16* __restrict__ w2l,
    const float* __restrict__ SW1, const float* __restrict__ Sb1,
    const float* __restrict__ Sb2,
    const float* __restrict__ SW3, const float* __restrict__ Sb3,
    float* __restrict__ out)
{
    __shared__ __align__(16) u16 F[2 * 16384];   // 64 KB feature frags (hi, lo)
    __shared__ float red[4][2][16];

    const int t   = threadIdx.x;
    const int w   = t >> 6;
    const int l   = t & 63;
    const int l15 = l & 15;
    const int l4  = l >> 4;
    const int p0  = blockIdx.x * PBM;

    // pair endpoints + logdeg for pairs l15 (group 0) and 16+l15 (group 1)
    const int si0 = pairs[(size_t)(p0 + l15) * 2 + 0];
    const int di0 = pairs[(size_t)(p0 + l15) * 2 + 1];
    const int si1 = pairs[(size_t)(p0 + 16 + l15) * 2 + 0];
    const int di1 = pairs[(size_t)(p0 + 16 + l15) * 2 + 1];
    const float ldS0 = logdeg[si0], ldD0 = logdeg[di0];
    const float ldS1 = logdeg[si1], ldD1 = logdeg[di1];

    // ---- phase 0: gather z, build features, split hi/lo, conflict-free stores ----
    {
        const int c0 = w * 32 + l4 * 8;            // channel run [c0, c0+8)
        #pragma unroll
        for (int m = 0; m < 2; ++m) {
            const int si = m ? si1 : si0;
            const int di = m ? di1 : di0;
            float s[8], d[8];
            *reinterpret_cast<float4*>(&s[0]) = *reinterpret_cast<const float4*>(z + (size_t)si * EMB + c0);
            *reinterpret_cast<float4*>(&s[4]) = *reinterpret_cast<const float4*>(z + (size_t)si * EMB + c0 + 4);
            *reinterpret_cast<float4*>(&d[0]) = *reinterpret_cast<const float4*>(z + (size_t)di * EMB + c0);
            *reinterpret_cast<float4*>(&d[4]) = *reinterpret_cast<const float4*>(z + (size_t)di * EMB + c0 + 4);
            float p[8], ad[8];
            #pragma unroll
            for (int e = 0; e < 8; ++e) { p[e] = s[e] * d[e]; ad[e] = fabsf(s[e] - d[e]); }

            #define W8(vals, grp) { \
                u16x8 hv, lv; \
                _Pragma("unroll") \
                for (int jj = 0; jj < 8; ++jj) { \
                    const u16 hh = f2bf((vals)[jj]); \
                    hv[jj] = hh; \
                    lv[jj] = f2bf((vals)[jj] - bf2f(hh)); \
                } \
                const int blk = m * 16 + (grp) * 4 + w; \
                *reinterpret_cast<u16x8*>(&F[blk * 512 + l * 8])         = hv; \
                *reinterpret_cast<u16x8*>(&F[16384 + blk * 512 + l * 8]) = lv; }

            W8(s, 0); W8(d, 1); W8(p, 2); W8(ad, 3);
            #undef W8
        }
    }
    __syncthreads();

    // ---- layer 1: acc[m][nt] over K=512; A=weights(L2), B=features(LDS) ----
    f32x4 acc[4][2];
    #pragma unroll
    for (int m = 0; m < 4; ++m) { acc[m][0] = (f32x4){0,0,0,0}; acc[m][1] = (f32x4){0,0,0,0}; }

    {
        const int aoff = l * 8;
        #pragma unroll 2
        for (int ks = 0; ks < 16; ++ks) {
            bf16x8 fh0 = *reinterpret_cast<const bf16x8*>(&F[(ks)      * 512 + aoff]);
            bf16x8 fh1 = *reinterpret_cast<const bf16x8*>(&F[(16 + ks) * 512 + aoff]);
            bf16x8 fl0 = *reinterpret_cast<const bf16x8*>(&F[16384 + (ks)      * 512 + aoff]);
            bf16x8 fl1 = *reinterpret_cast<const bf16x8*>(&F[16384 + (16 + ks) * 512 + aoff]);
            #pragma unroll
            for (int m = 0; m < 4; ++m) {
                const int mt = w * 4 + m;
                const size_t bo = ((size_t)(mt * 16 + ks) * 64 + l) * 8;
                bf16x8 ah = *reinterpret_cast<const bf16x8*>(&w1h[bo]);
                bf16x8 al = *reinterpret_cast<const bf16x8*>(&w1l[bo]);
                acc[m][0] = __builtin_amdgcn_mfma_f32_16x16x32_bf16(ah, fh0, acc[m][0], 0, 0, 0);
                acc[m][1] = __builtin_amdgcn_mfma_f32_16x16x32_bf16(ah, fh1, acc[m][1], 0, 0, 0);
                acc[m][0] = __builtin_amdgcn_mfma_f32_16x16x32_bf16(al, fh0, acc[m][0], 0, 0, 0);
                acc[m][1] = __builtin_amdgcn_mfma_f32_16x16x32_bf16(al, fh1, acc[m][1], 0, 0, 0);
                acc[m][0] = __builtin_amdgcn_mfma_f32_16x16x32_bf16(ah, fl0, acc[m][0], 0, 0, 0);
                acc[m][1] = __builtin_amdgcn_mfma_f32_16x16x32_bf16(ah, fl1, acc[m][1], 0, 0, 0);
            }
        }
    }
    __syncthreads();   // all waves done reading F

    // ---- epilogue 1: bias + logdeg rank-2 + relu; packed b64 stores of s1 frags ----
    // s1 frag layout (layer-2 B-operand): elem = half*8192 + (nt*8+ks2)*512 + l2*8 + j2
    u16* s1h = F;
    u16* s1l = F + 8192;
    #pragma unroll
    for (int m = 0; m < 4; ++m) {
        const int mt = w * 4 + m;
        const int nb = mt * 16 + l4 * 4;           // 4 consecutive n
        float sb[4], wa[4], wb[4];
        *reinterpret_cast<float4*>(sb) = *reinterpret_cast<const float4*>(&Sb1[nb]);
        *reinterpret_cast<float4*>(wa) = *reinterpret_cast<const float4*>(&SW1[(size_t)512 * HID + nb]);
        *reinterpret_cast<float4*>(wb) = *reinterpret_cast<const float4*>(&SW1[(size_t)513 * HID + nb]);
        #pragma unroll
        for (int nt = 0; nt < 2; ++nt) {
            const float lS = nt ? ldS1 : ldS0;
            const float lD = nt ? ldD1 : ldD0;
            u16x4 hv, lv;
            #pragma unroll
            for (int r = 0; r < 4; ++r) {
                float v = acc[m][nt][r] + sb[r];
                v = fmaf(lS, wa[r], v);
                v = fmaf(lD, wb[r], v);
                v = fmaxf(v, 0.0f);
                const u16 hh = f2bf(v);
                hv[r] = hh;
                lv[r] = f2bf(v - bf2f(hh));
            }
            const int base = (nt * 8 + (mt >> 1)) * 512
                           + (l15 + 16 * ((mt & 1) * 2 + (l4 >> 1))) * 8
                           + (l4 & 1) * 4;
            *reinterpret_cast<u16x4*>(&s1h[base]) = hv;
            *reinterpret_cast<u16x4*>(&s1l[base]) = lv;
        }
    }
    __syncthreads();

    // ---- layer 2: acc2[m][nt] over K=256 ----
    f32x4 acc2[2][2];
    #pragma unroll
    for (int m = 0; m < 2; ++m) { acc2[m][0] = (f32x4){0,0,0,0}; acc2[m][1] = (f32x4){0,0,0,0}; }

    {
        const int aoff = l * 8;
        #pragma unroll 2
        for (int ks = 0; ks < 8; ++ks) {
            bf16x8 fh0 = *reinterpret_cast<const bf16x8*>(&s1h[(ks)     * 512 + aoff]);
            bf16x8 fh1 = *reinterpret_cast<const bf16x8*>(&s1h[(8 + ks) * 512 + aoff]);
            bf16x8 fl0 = *reinterpret_cast<const bf16x8*>(&s1l[(ks)     * 512 + aoff]);
            bf16x8 fl1 = *reinterpret_cast<const bf16x8*>(&s1l[(8 + ks) * 512 + aoff]);
            #pragma unroll
            for (int m = 0; m < 2; ++m) {
                const int mt = w * 2 + m;
                const size_t bo = ((size_t)(mt * 8 + ks) * 64 + l) * 8;
                bf16x8 ah = *reinterpret_cast<const bf16x8*>(&w2h[bo]);
                bf16x8 al = *reinterpret_cast<const bf16x8*>(&w2l[bo]);
                acc2[m][0] = __builtin_amdgcn_mfma_f32_16x16x32_bf16(ah, fh0, acc2[m][0], 0, 0, 0);
                acc2[m][1] = __builtin_amdgcn_mfma_f32_16x16x32_bf16(ah, fh1, acc2[m][1], 0, 0, 0);
                acc2[m][0] = __builtin_amdgcn_mfma_f32_16x16x32_bf16(al, fh0, acc2[m][0], 0, 0, 0);
                acc2[m][1] = __builtin_amdgcn_mfma_f32_16x16x32_bf16(al, fh1, acc2[m][1], 0, 0, 0);
                acc2[m][0] = __builtin_amdgcn_mfma_f32_16x16x32_bf16(ah, fl0, acc2[m][0], 0, 0, 0);
                acc2[m][1] = __builtin_amdgcn_mfma_f32_16x16x32_bf16(ah, fl1, acc2[m][1], 0, 0, 0);
            }
        }
    }

    // ---- epilogue 2 + layer 3: register-local dot with SW3, cross-lane reduce ----
    float part0 = 0.0f, part1 = 0.0f;
    #pragma unroll
    for (int m = 0; m < 2; ++m) {
        const int nb = (w * 2 + m) * 16 + l4 * 4;  // 4 consecutive n2
        float sb[4], w3[4];
        *reinterpret_cast<float4*>(sb) = *reinterpret_cast<const float4*>(&Sb2[nb]);
        *reinterpret_cast<float4*>(w3) = *reinterpret_cast<const float4*>(&SW3[nb]);
        #pragma unroll
        for (int r = 0; r < 4; ++r) {
            part0 = fmaf(fmaxf(acc2[m][0][r] + sb[r], 0.0f), w3[r], part0);
            part1 = fmaf(fmaxf(acc2[m][1][r] + sb[r], 0.0f), w3[r], part1);
        }
    }
    part0 += __shfl_xor(part0, 16); part0 += __shfl_xor(part0, 32);
    part1 += __shfl_xor(part1, 16); part1 += __shfl_xor(part1, 32);
    if (l < 16) { red[w][0][l15] = part0; red[w][1][l15] = part1; }
    __syncthreads();

    if (t < 32) {
        const int pg = t >> 4, pp = t & 15;
        float v = red[0][pg][pp] + red[1][pg][pp] + red[2][pg][pp] + red[3][pg][pp] + Sb3[0];
        if (isnan(v)) v = 0.0f;
        else if (isinf(v)) v = (v > 0.0f) ? 20.0f : -20.0f;
        out[p0 + t] = v;
    }
}

// ---------------------------------------------------------------------------
extern "C" void kernel_launch(void* const* d_in, const int* in_sizes, int n_in,
                              void* d_out, int out_size, void* d_ws, size_t ws_size,
                              hipStream_t stream)
{
    const float* x        = (const float*)d_in[0];
    // d_in[1] = edge_index : unused by the reference
    const int*   pairs    = (const int*)d_in[2];
    const float* x_mean   = (const float*)d_in[3];
    const float* x_std    = (const float*)d_in[4];
    const float* logdeg   = (const float*)d_in[5];
    const float* W1       = (const float*)d_in[6];
    const float* b1       = (const float*)d_in[7];
    const float* bn_gamma = (const float*)d_in[8];
    const float* bn_beta  = (const float*)d_in[9];
    const float* bn_mean  = (const float*)d_in[10];
    const float* bn_var   = (const float*)d_in[11];
    const float* W2       = (const float*)d_in[12];
    const float* b2       = (const float*)d_in[13];
    const float* SW1      = (const float*)d_in[14];
    const float* Sb1      = (const float*)d_in[15];
    const float* SW2      = (const float*)d_in[16];
    const float* Sb2      = (const float*)d_in[17];
    const float* SW3      = (const float*)d_in[18];
    const float* Sb3      = (const float*)d_in[19];

    float* outp = (float*)d_out;

    // ws layout
    char* wsb = (char*)d_ws;
    float* zbuf = (float*)wsb;                          // 51,200,000 B
    u16* w1h = (u16*)(wsb + 51200000);                  // 262144 B
    u16* w1l = (u16*)(wsb + 51462144);                  // 262144 B
    u16* w2h = (u16*)(wsb + 51724288);                  // 65536 B
    u16* w2l = (u16*)(wsb + 51789824);                  // 65536 B

    prep_weights<<<640, 256, 0, stream>>>(SW1, SW2, w1h, w1l, w2h, w2l);

    node_mlp_kernel<<<N_NODES / TA, 256, 0, stream>>>(
        x, x_mean, x_std, W1, b1, bn_gamma, bn_beta, bn_mean, bn_var, W2, b2, zbuf);

    pair_mfma_kernel<<<N_PAIRS / PBM, 256, 0, stream>>>(
        zbuf, pairs, logdeg, w1h, w1l, w2h, w2l, SW1, Sb1, Sb2, SW3, Sb3, outp);
}

// Round 4
// 635.153 us; speedup vs baseline: 5.4103x; 1.2690x over previous
//
#include <hip/hip_runtime.h>
#include <math.h>

typedef unsigned short u16;
typedef __attribute__((ext_vector_type(8))) short bf16x8;
typedef __attribute__((ext_vector_type(4))) unsigned short u16x4;
typedef __attribute__((ext_vector_type(8))) unsigned short u16x8;
typedef __attribute__((ext_vector_type(4))) float f32x4;

#define N_NODES 100000
#define IN_CH 128
#define HID 256
#define EMB 128
#define N_PAIRS 500000
#define BN_EPS 1e-5f

#define TA 32   // nodes per block (kernel A)
#define PBM 64  // pairs per block (kernel B)

// ---- bf16 split helpers (round-to-nearest-even) ----
__device__ __forceinline__ u16 f2bf(float f) {
    unsigned u = __builtin_bit_cast(unsigned, f);
    unsigned r = u + 0x7FFFu + ((u >> 16) & 1u);
    return (u16)(r >> 16);
}
__device__ __forceinline__ float bf2f(u16 h) {
    unsigned u = ((unsigned)h) << 16;
    return __builtin_bit_cast(float, u);
}

// ---------------------------------------------------------------------------
// Weight prep into MFMA A-operand fragment-linear layout (weights on M-side):
// idx = ((mt*KS + ks)*64 + l)*8 + j ; value = W[k][n], n = mt*16 + (l&15),
// k = ks*32 + (l>>4)*8 + j.
// ---------------------------------------------------------------------------
__global__ __launch_bounds__(256) void prep_weights(
    const float* __restrict__ SW1, const float* __restrict__ SW2,
    u16* __restrict__ w1h, u16* __restrict__ w1l,
    u16* __restrict__ w2h, u16* __restrict__ w2l)
{
    const int tid = blockIdx.x * 256 + threadIdx.x;
    if (tid < 131072) {                       // W1^T frags: 16 mt x 16 ks
        const int j = tid & 7, l = (tid >> 3) & 63, ks = (tid >> 9) & 15, mt = tid >> 13;
        const int n = mt * 16 + (l & 15);
        const int k = ks * 32 + ((l >> 4) << 3) + j;
        const float v = SW1[(size_t)k * HID + n];
        const u16 h = f2bf(v);
        w1h[tid] = h;
        w1l[tid] = f2bf(v - bf2f(h));
    } else if (tid < 131072 + 32768) {        // W2^T frags: 8 mt x 8 ks
        const int t2 = tid - 131072;
        const int j = t2 & 7, l = (t2 >> 3) & 63, ks = (t2 >> 9) & 7, mt = t2 >> 12;
        const int n = mt * 16 + (l & 15);
        const int k = ks * 32 + ((l >> 4) << 3) + j;
        const float v = SW2[(size_t)k * (HID / 2) + n];
        const u16 h = f2bf(v);
        w2h[t2] = h;
        w2l[t2] = f2bf(v - bf2f(h));
    }
}

// ---------------------------------------------------------------------------
// Kernel A: z = relu( relu(BN(clip((x-mean)/std) @ W1 + b1)) @ W2 + b2 )
// (unchanged — fp32 register-tiled)
// ---------------------------------------------------------------------------
__global__ __launch_bounds__(256) void node_mlp_kernel(
    const float* __restrict__ x,
    const float* __restrict__ x_mean,
    const float* __restrict__ x_std,
    const float* __restrict__ W1,
    const float* __restrict__ b1,
    const float* __restrict__ bn_gamma,
    const float* __restrict__ bn_beta,
    const float* __restrict__ bn_mean,
    const float* __restrict__ bn_var,
    const float* __restrict__ W2,
    const float* __restrict__ b2,
    float* __restrict__ z)
{
    __shared__ __align__(16) float xfT[IN_CH][36];
    __shared__ __align__(16) float hT[HID][36];

    const int t  = threadIdx.x;
    const int n0 = blockIdx.x * TA;

    for (int f = t; f < TA * (IN_CH / 4); f += 256) {
        const int n  = f >> 5;
        const int cg = f & 31;
        float4 v = *reinterpret_cast<const float4*>(x + (size_t)(n0 + n) * IN_CH + cg * 4);
        float vv[4] = {v.x, v.y, v.z, v.w};
        #pragma unroll
        for (int e = 0; e < 4; ++e) {
            const int c = cg * 4 + e;
            float val = vv[e];
            if (!isfinite(val)) val = 0.0f;
            val = (val - x_mean[c]) / x_std[c];
            val = fminf(fmaxf(val, -10.0f), 10.0f);
            xfT[c][n] = val;
        }
    }
    __syncthreads();

    const int i0 = t >> 6;
    const int j  = t & 63;

    {
        float acc[8][4];
        #pragma unroll
        for (int r = 0; r < 8; ++r)
            #pragma unroll
            for (int c = 0; c < 4; ++c) acc[r][c] = 0.0f;

        #pragma unroll 4
        for (int k = 0; k < IN_CH; ++k) {
            float a[8];
            *reinterpret_cast<float4*>(&a[0]) = *reinterpret_cast<const float4*>(&xfT[k][i0 * 8]);
            *reinterpret_cast<float4*>(&a[4]) = *reinterpret_cast<const float4*>(&xfT[k][i0 * 8 + 4]);
            float w[4];
            *reinterpret_cast<float4*>(w) = *reinterpret_cast<const float4*>(W1 + (size_t)k * HID + j * 4);
            #pragma unroll
            for (int r = 0; r < 8; ++r)
                #pragma unroll
                for (int c = 0; c < 4; ++c)
                    acc[r][c] = fmaf(a[r], w[c], acc[r][c]);
        }

        float b1v[4], gv[4], bev[4], mv[4], vv[4];
        *reinterpret_cast<float4*>(b1v) = *reinterpret_cast<const float4*>(b1 + j * 4);
        *reinterpret_cast<float4*>(gv)  = *reinterpret_cast<const float4*>(bn_gamma + j * 4);
        *reinterpret_cast<float4*>(bev) = *reinterpret_cast<const float4*>(bn_beta + j * 4);
        *reinterpret_cast<float4*>(mv)  = *reinterpret_cast<const float4*>(bn_mean + j * 4);
        *reinterpret_cast<float4*>(vv)  = *reinterpret_cast<const float4*>(bn_var + j * 4);

        #pragma unroll
        for (int c = 0; c < 4; ++c) {
            const float scale = gv[c] * rsqrtf(vv[c] + BN_EPS);
            float tmp[8];
            #pragma unroll
            for (int r = 0; r < 8; ++r) {
                const float hv = (acc[r][c] + b1v[c] - mv[c]) * scale + bev[c];
                tmp[r] = fmaxf(hv, 0.0f);
            }
            *reinterpret_cast<float4*>(&hT[j * 4 + c][i0 * 8])     = *reinterpret_cast<float4*>(&tmp[0]);
            *reinterpret_cast<float4*>(&hT[j * 4 + c][i0 * 8 + 4]) = *reinterpret_cast<float4*>(&tmp[4]);
        }
    }
    __syncthreads();

    {
        float acc[8][2];
        #pragma unroll
        for (int r = 0; r < 8; ++r) { acc[r][0] = 0.0f; acc[r][1] = 0.0f; }

        #pragma unroll 4
        for (int k = 0; k < HID; ++k) {
            float a[8];
            *reinterpret_cast<float4*>(&a[0]) = *reinterpret_cast<const float4*>(&hT[k][i0 * 8]);
            *reinterpret_cast<float4*>(&a[4]) = *reinterpret_cast<const float4*>(&hT[k][i0 * 8 + 4]);
            const float2 w = *reinterpret_cast<const float2*>(W2 + (size_t)k * EMB + j * 2);
            #pragma unroll
            for (int r = 0; r < 8; ++r) {
                acc[r][0] = fmaf(a[r], w.x, acc[r][0]);
                acc[r][1] = fmaf(a[r], w.y, acc[r][1]);
            }
        }
        const float2 b2v = *reinterpret_cast<const float2*>(b2 + j * 2);
        #pragma unroll
        for (int r = 0; r < 8; ++r) {
            float2 o;
            o.x = fmaxf(acc[r][0] + b2v.x, 0.0f);
            o.y = fmaxf(acc[r][1] + b2v.y, 0.0f);
            *reinterpret_cast<float2*>(z + (size_t)(n0 + i0 * 8 + r) * EMB + j * 2) = o;
        }
    }
}

// ---------------------------------------------------------------------------
// Kernel B (MFMA): 64 pairs per block, 4 waves. Two-pass K for layer 1:
//   pass A: k in [0,256)  = [src | dst] chunks staged in LDS (hi+lo bf16)
//   pass B: k in [256,512) = [src*dst | |src-dst|] chunks, rebuilt from the
//           thread's own pass-A LDS data, overwriting the same slots.
// Weights (A-operand) stream from L2 with a 1-deep register double-buffer.
// Feature frag layout (B-operand), slot s, group nt:
//   F[(s*4+nt)*512 + l*8 + j]  <-> feat[pair = nt*16+(l&15)][k = s*32+(l>>4)*8+j]
// ---------------------------------------------------------------------------
__global__ __launch_bounds__(256, 2) void pair_mfma_kernel(
    const float* __restrict__ z,
    const int* __restrict__ pairs,
    const float* __restrict__ logdeg,
    const u16* __restrict__ w1h, const u16* __restrict__ w1l,
    const u16* __restrict__ w2h, const u16* __restrict__ w2l,
    const float* __restrict__ SW1, const float* __restrict__ Sb1,
    const float* __restrict__ Sb2,
    const float* __restrict__ SW3, const float* __restrict__ Sb3,
    float* __restrict__ out)
{
    __shared__ __align__(16) u16 F[2 * 16384];   // 64 KB: [half][slot 0..7][nt 0..3][512]
    __shared__ float red[4][4][16];

    const int t   = threadIdx.x;
    const int w   = t >> 6;
    const int l   = t & 63;
    const int l15 = l & 15;
    const int l4  = l >> 4;
    const int p0  = blockIdx.x * PBM;

    // split 32 values (channel run) into hi/lo frags at LDS slot `slot`, pair `l`
    #define STORE_FEAT(vals, slot) { \
        _Pragma("unroll") \
        for (int sub = 0; sub < 4; ++sub) { \
            u16x8 hv, lv; \
            _Pragma("unroll") \
            for (int jj = 0; jj < 8; ++jj) { \
                const float vvv = (vals)[sub * 8 + jj]; \
                const u16 hh = f2bf(vvv); \
                hv[jj] = hh; \
                lv[jj] = f2bf(vvv - bf2f(hh)); \
            } \
            const int base = ((slot) * 4 + l4) * 512 + (l15 + 16 * sub) * 8; \
            *reinterpret_cast<u16x8*>(&F[base])         = hv; \
            *reinterpret_cast<u16x8*>(&F[16384 + base]) = lv; \
        } }

    // ---- phase 0: gather s,d (pair = l, channel chunk = w*32..+32) ----
    {
        const int gp  = min(p0 + l, N_PAIRS - 1);
        const int gsi = pairs[(size_t)gp * 2 + 0];
        const int gdi = pairs[(size_t)gp * 2 + 1];
        const float* zs = z + (size_t)gsi * EMB + w * 32;
        const float* zd = z + (size_t)gdi * EMB + w * 32;
        float sv[32], dv[32];
        #pragma unroll
        for (int q = 0; q < 8; ++q) {
            *reinterpret_cast<float4*>(&sv[q * 4]) = *reinterpret_cast<const float4*>(zs + q * 4);
            *reinterpret_cast<float4*>(&dv[q * 4]) = *reinterpret_cast<const float4*>(zd + q * 4);
        }
        STORE_FEAT(sv, w);       // k in [w*32, w*32+32)
        STORE_FEAT(dv, 4 + w);   // k in [128 + w*32, ...)
    }
    __syncthreads();

    // ---- layer 1: C^T = W1^T @ feat^T, K=512 in two 256-passes ----
    f32x4 acc[4][4];
    #pragma unroll
    for (int m = 0; m < 4; ++m)
        #pragma unroll
        for (int nt = 0; nt < 4; ++nt) acc[m][nt] = (f32x4){0.f, 0.f, 0.f, 0.f};

    auto run_pass = [&](int kbase) {
        bf16x8 wbh[2][4], wbl[2][4];
        #pragma unroll
        for (int m = 0; m < 4; ++m) {
            const size_t bo = ((size_t)((w * 4 + m) * 16 + kbase) * 64 + l) * 8;
            wbh[0][m] = *reinterpret_cast<const bf16x8*>(&w1h[bo]);
            wbl[0][m] = *reinterpret_cast<const bf16x8*>(&w1l[bo]);
        }
        #pragma unroll
        for (int ks = 0; ks < 8; ++ks) {
            const int cur = ks & 1;
            if (ks < 7) {
                #pragma unroll
                for (int m = 0; m < 4; ++m) {
                    const size_t bo = ((size_t)((w * 4 + m) * 16 + kbase + ks + 1) * 64 + l) * 8;
                    wbh[cur ^ 1][m] = *reinterpret_cast<const bf16x8*>(&w1h[bo]);
                    wbl[cur ^ 1][m] = *reinterpret_cast<const bf16x8*>(&w1l[bo]);
                }
            }
            bf16x8 fh[4], fl[4];
            #pragma unroll
            for (int nt = 0; nt < 4; ++nt) {
                const int fb = (ks * 4 + nt) * 512 + l * 8;
                fh[nt] = *reinterpret_cast<const bf16x8*>(&F[fb]);
                fl[nt] = *reinterpret_cast<const bf16x8*>(&F[16384 + fb]);
            }
            #pragma unroll
            for (int m = 0; m < 4; ++m) {
                #pragma unroll
                for (int nt = 0; nt < 4; ++nt) {
                    acc[m][nt] = __builtin_amdgcn_mfma_f32_16x16x32_bf16(wbh[cur][m], fh[nt], acc[m][nt], 0, 0, 0);
                    acc[m][nt] = __builtin_amdgcn_mfma_f32_16x16x32_bf16(wbl[cur][m], fh[nt], acc[m][nt], 0, 0, 0);
                    acc[m][nt] = __builtin_amdgcn_mfma_f32_16x16x32_bf16(wbh[cur][m], fl[nt], acc[m][nt], 0, 0, 0);
                }
            }
        }
    };

    run_pass(0);
    __syncthreads();   // all waves done reading pass-A frags

    // ---- transition: rebuild p = s*d, ad = |s-d| from own quantized s,d ----
    {
        float pv[32], av[32];
        #pragma unroll
        for (int sub = 0; sub < 4; ++sub) {
            const int bs = (w * 4 + l4) * 512 + (l15 + 16 * sub) * 8;
            const int bd = ((4 + w) * 4 + l4) * 512 + (l15 + 16 * sub) * 8;
            u16x8 sh = *reinterpret_cast<u16x8*>(&F[bs]);
            u16x8 sl = *reinterpret_cast<u16x8*>(&F[16384 + bs]);
            u16x8 dh = *reinterpret_cast<u16x8*>(&F[bd]);
            u16x8 dl = *reinterpret_cast<u16x8*>(&F[16384 + bd]);
            #pragma unroll
            for (int jj = 0; jj < 8; ++jj) {
                const float sf = bf2f(sh[jj]) + bf2f(sl[jj]);
                const float df = bf2f(dh[jj]) + bf2f(dl[jj]);
                pv[sub * 8 + jj] = sf * df;
                av[sub * 8 + jj] = fabsf(sf - df);
            }
        }
        STORE_FEAT(pv, w);       // k = 256 + w*32 ... (global ks = 8+w -> slot w)
        STORE_FEAT(av, 4 + w);   // k = 384 + w*32 ... (global ks = 12+w -> slot 4+w)
    }
    __syncthreads();

    run_pass(8);
    __syncthreads();   // all waves done reading pass-B frags

    // ---- epilogue 1: bias + logdeg rank-2 + relu; s1 frags overwrite F ----
    float ldS[4], ldD[4];
    #pragma unroll
    for (int nt = 0; nt < 4; ++nt) {
        const int pidx = min(p0 + nt * 16 + l15, N_PAIRS - 1);
        ldS[nt] = logdeg[pairs[(size_t)pidx * 2 + 0]];
        ldD[nt] = logdeg[pairs[(size_t)pidx * 2 + 1]];
    }
    #pragma unroll
    for (int m = 0; m < 4; ++m) {
        const int mt = w * 4 + m;
        const int nb = mt * 16 + l4 * 4;
        float sb[4], wa[4], wb[4];
        *reinterpret_cast<float4*>(sb) = *reinterpret_cast<const float4*>(&Sb1[nb]);
        *reinterpret_cast<float4*>(wa) = *reinterpret_cast<const float4*>(&SW1[(size_t)512 * HID + nb]);
        *reinterpret_cast<float4*>(wb) = *reinterpret_cast<const float4*>(&SW1[(size_t)513 * HID + nb]);
        #pragma unroll
        for (int nt = 0; nt < 4; ++nt) {
            u16x4 hv, lv;
            #pragma unroll
            for (int r = 0; r < 4; ++r) {
                float v = acc[m][nt][r] + sb[r];
                v = fmaf(ldS[nt], wa[r], v);
                v = fmaf(ldD[nt], wb[r], v);
                v = fmaxf(v, 0.0f);
                const u16 hh = f2bf(v);
                hv[r] = hh;
                lv[r] = f2bf(v - bf2f(hh));
            }
            const int base = (nt * 8 + (mt >> 1)) * 512
                           + (l15 + 16 * ((mt & 1) * 2 + (l4 >> 1))) * 8
                           + (l4 & 1) * 4;
            *reinterpret_cast<u16x4*>(&F[base])         = hv;
            *reinterpret_cast<u16x4*>(&F[16384 + base]) = lv;
        }
    }
    __syncthreads();

    // ---- layer 2: K=256, s1 frags from LDS, W2 frags prefetched from L2 ----
    f32x4 acc2[2][4];
    #pragma unroll
    for (int m = 0; m < 2; ++m)
        #pragma unroll
        for (int nt = 0; nt < 4; ++nt) acc2[m][nt] = (f32x4){0.f, 0.f, 0.f, 0.f};

    {
        bf16x8 wbh[2][2], wbl[2][2];
        #pragma unroll
        for (int m = 0; m < 2; ++m) {
            const size_t bo = ((size_t)((w * 2 + m) * 8) * 64 + l) * 8;
            wbh[0][m] = *reinterpret_cast<const bf16x8*>(&w2h[bo]);
            wbl[0][m] = *reinterpret_cast<const bf16x8*>(&w2l[bo]);
        }
        #pragma unroll
        for (int ks = 0; ks < 8; ++ks) {
            const int cur = ks & 1;
            if (ks < 7) {
                #pragma unroll
                for (int m = 0; m < 2; ++m) {
                    const size_t bo = ((size_t)((w * 2 + m) * 8 + ks + 1) * 64 + l) * 8;
                    wbh[cur ^ 1][m] = *reinterpret_cast<const bf16x8*>(&w2h[bo]);
                    wbl[cur ^ 1][m] = *reinterpret_cast<const bf16x8*>(&w2l[bo]);
                }
            }
            bf16x8 fh[4], fl[4];
            #pragma unroll
            for (int nt = 0; nt < 4; ++nt) {
                const int fb = (nt * 8 + ks) * 512 + l * 8;
                fh[nt] = *reinterpret_cast<const bf16x8*>(&F[fb]);
                fl[nt] = *reinterpret_cast<const bf16x8*>(&F[16384 + fb]);
            }
            #pragma unroll
            for (int m = 0; m < 2; ++m) {
                #pragma unroll
                for (int nt = 0; nt < 4; ++nt) {
                    acc2[m][nt] = __builtin_amdgcn_mfma_f32_16x16x32_bf16(wbh[cur][m], fh[nt], acc2[m][nt], 0, 0, 0);
                    acc2[m][nt] = __builtin_amdgcn_mfma_f32_16x16x32_bf16(wbl[cur][m], fh[nt], acc2[m][nt], 0, 0, 0);
                    acc2[m][nt] = __builtin_amdgcn_mfma_f32_16x16x32_bf16(wbh[cur][m], fl[nt], acc2[m][nt], 0, 0, 0);
                }
            }
        }
    }

    // ---- epilogue 2 + layer 3: register dot with SW3, cross-lane+wave reduce ----
    {
        float part[4] = {0.f, 0.f, 0.f, 0.f};
        #pragma unroll
        for (int m = 0; m < 2; ++m) {
            const int nb2 = (w * 2 + m) * 16 + l4 * 4;
            float sb[4], w3[4];
            *reinterpret_cast<float4*>(sb) = *reinterpret_cast<const float4*>(&Sb2[nb2]);
            *reinterpret_cast<float4*>(w3) = *reinterpret_cast<const float4*>(&SW3[nb2]);
            #pragma unroll
            for (int nt = 0; nt < 4; ++nt)
                #pragma unroll
                for (int r = 0; r < 4; ++r)
                    part[nt] = fmaf(fmaxf(acc2[m][nt][r] + sb[r], 0.0f), w3[r], part[nt]);
        }
        #pragma unroll
        for (int nt = 0; nt < 4; ++nt) {
            part[nt] += __shfl_xor(part[nt], 16);
            part[nt] += __shfl_xor(part[nt], 32);
        }
        if (l < 16) {
            #pragma unroll
            for (int nt = 0; nt < 4; ++nt) red[w][nt][l15] = part[nt];
        }
    }
    __syncthreads();

    if (t < 64) {
        const int nt = t >> 4, pp = t & 15;
        float v = red[0][nt][pp] + red[1][nt][pp] + red[2][nt][pp] + red[3][nt][pp] + Sb3[0];
        if (isnan(v)) v = 0.0f;
        else if (isinf(v)) v = (v > 0.0f) ? 20.0f : -20.0f;
        const int pidx = p0 + nt * 16 + pp;
        if (pidx < N_PAIRS) out[pidx] = v;
    }
    #undef STORE_FEAT
}

// ---------------------------------------------------------------------------
extern "C" void kernel_launch(void* const* d_in, const int* in_sizes, int n_in,
                              void* d_out, int out_size, void* d_ws, size_t ws_size,
                              hipStream_t stream)
{
    const float* x        = (const float*)d_in[0];
    // d_in[1] = edge_index : unused by the reference
    const int*   pairs    = (const int*)d_in[2];
    const float* x_mean   = (const float*)d_in[3];
    const float* x_std    = (const float*)d_in[4];
    const float* logdeg   = (const float*)d_in[5];
    const float* W1       = (const float*)d_in[6];
    const float* b1       = (const float*)d_in[7];
    const float* bn_gamma = (const float*)d_in[8];
    const float* bn_beta  = (const float*)d_in[9];
    const float* bn_mean  = (const float*)d_in[10];
    const float* bn_var   = (const float*)d_in[11];
    const float* W2       = (const float*)d_in[12];
    const float* b2       = (const float*)d_in[13];
    const float* SW1      = (const float*)d_in[14];
    const float* Sb1      = (const float*)d_in[15];
    const float* SW2      = (const float*)d_in[16];
    const float* Sb2      = (const float*)d_in[17];
    const float* SW3      = (const float*)d_in[18];
    const float* Sb3      = (const float*)d_in[19];

    float* outp = (float*)d_out;

    // ws layout
    char* wsb = (char*)d_ws;
    float* zbuf = (float*)wsb;                          // 51,200,000 B
    u16* w1h = (u16*)(wsb + 51200000);                  // 262144 B
    u16* w1l = (u16*)(wsb + 51462144);                  // 262144 B
    u16* w2h = (u16*)(wsb + 51724288);                  // 65536 B
    u16* w2l = (u16*)(wsb + 51789824);                  // 65536 B

    prep_weights<<<640, 256, 0, stream>>>(SW1, SW2, w1h, w1l, w2h, w2l);

    node_mlp_kernel<<<N_NODES / TA, 256, 0, stream>>>(
        x, x_mean, x_std, W1, b1, bn_gamma, bn_beta, bn_mean, bn_var, W2, b2, zbuf);

    pair_mfma_kernel<<<(N_PAIRS + PBM - 1) / PBM, 256, 0, stream>>>(
        zbuf, pairs, logdeg, w1h, w1l, w2h, w2l, SW1, Sb1, Sb2, SW3, Sb3, outp);
}